// Round 16
// baseline (206.990 us; speedup 1.0000x reference)
//
#include <hip/hip_runtime.h>
#include <hip/hip_fp16.h>

#define NN 100000
#define NE 3200000
#define NG 2048
#define HD 64
#define BUKSZ 256         // nodes per bucket
#define NBUK 391          // ceil(NN / BUKSZ)
#define NB 512            // stage blocks
#define CHUNK 6250        // NE / NB exactly
#define CAP 9216          // padded edge capacity per bucket (mean 8192, sigma ~90)

// NOTE: int LDS atomics only (native ds ops). Float LDS atomicAdd is a CAS
// loop on this target (R8: 204.8M of them = 1342us) -- never use it.
// NOTE2 (R9): latency-bound gathers want max independent waves; do not make
// one wave process multiple nodes behind a block barrier.
// NOTE3 (R11): shfl with divergent srcLane under half-divergent loop bounds is
// undefined (reads exec-masked lanes). readlane with compile-time lane is safe.
// NOTE4 (R15): gather was VMEM-issue-bound at 4B/lane loads; 16B/lane loads
// cover 4 rows per instruction (4x fewer VMEM instrs).
// NOTE5 (R16): small dense GEMMs: LDS-read-per-FMA is the bottleneck (21% VALU);
// register-resident W-column + readlane broadcast makes it pure VALU.

// ---------------- init per-bucket cursors (absolute) ----------------

__global__ void init_k(int* __restrict__ bcur) {
    int t = blockIdx.x * blockDim.x + threadIdx.x;
    if (t <= NBUK) bcur[t] = t * CAP;
}

// ---------------- pass 1: block-local bucket sort -> padded bucket runs ----------------
// packed value: (dst & 255) << 17 | src   (src < 2^17)

__global__ __launch_bounds__(512) void stageA_k(
        const int* __restrict__ src, const int* __restrict__ dst,
        int* __restrict__ bcur, unsigned int* __restrict__ edges2) {
    __shared__ int hist[NBUK];
    __shared__ int exb[NBUK + 1];
    __shared__ int cur[NBUK];
    __shared__ int obase[NBUK];
    __shared__ int sc[512];
    __shared__ unsigned int svals[CHUNK];
    __shared__ unsigned short sbuk[CHUNK];   // bucket id per sorted slot
    int b = blockIdx.x, t = threadIdx.x;
    int base = b * CHUNK;
    for (int i = t; i < NBUK; i += 512) hist[i] = 0;
    __syncthreads();
    for (int i = t; i < CHUNK; i += 512)
        atomicAdd(&hist[dst[base + i] >> 8], 1);
    __syncthreads();
    int v = (t < NBUK) ? hist[t] : 0;
    sc[t] = v;
    __syncthreads();
    for (int o = 1; o < 512; o <<= 1) {
        int u = (t >= o) ? sc[t - o] : 0;
        __syncthreads();
        sc[t] += u;
        __syncthreads();
    }
    if (t < NBUK) {
        int excl = sc[t] - v;
        exb[t] = excl;
        cur[t] = excl;
        obase[t] = v ? atomicAdd(&bcur[t], v) : 0;
    }
    if (t == 0) exb[NBUK] = CHUNK;
    __syncthreads();
    for (int i = t; i < CHUNK; i += 512) {
        int d = dst[base + i];
        int s = src[base + i];
        int bk = d >> 8;
        int pos = atomicAdd(&cur[bk], 1);
        svals[pos] = ((unsigned int)(d & 255) << 17) | (unsigned int)s;
        sbuk[pos] = (unsigned short)bk;
    }
    __syncthreads();
    for (int i = t; i < CHUNK; i += 512) {
        int lo = (int)sbuk[i];
        edges2[obase[lo] + (i - exb[lo])] = svals[i];
    }
}

// ---------------- pass 2: per-bucket fine sort (in-place) + row info + dinv + xs ----------------

__global__ __launch_bounds__(512) void build1_k(
        const int* __restrict__ bcur, const float4* __restrict__ x,
        unsigned int* __restrict__ edges2, int* __restrict__ row_beg,
        int* __restrict__ row_deg, float* __restrict__ dinv,
        float4* __restrict__ xs) {
    __shared__ unsigned int ebuf[CAP];   // 36 KB
    __shared__ int deg[BUKSZ];
    __shared__ int sc[BUKSZ];
    __shared__ int cur[BUKSZ];
    int k = blockIdx.x, t = threadIdx.x;
    int base = k * CAP;
    int len = bcur[k] - base;
    if (t < BUKSZ) deg[t] = 0;
    __syncthreads();
    for (int i = t; i < len; i += 512) {
        unsigned int pv = edges2[base + i];
        ebuf[i] = pv;
        atomicAdd(&deg[pv >> 17], 1);
    }
    __syncthreads();
    int v = 0;
    if (t < BUKSZ) { v = deg[t]; sc[t] = v; }
    __syncthreads();
    for (int o = 1; o < BUKSZ; o <<= 1) {
        int u = 0;
        if (t < BUKSZ && t >= o) u = sc[t - o];
        __syncthreads();
        if (t < BUKSZ && t >= o) sc[t] += u;
        __syncthreads();
    }
    if (t < BUKSZ) {
        int excl = sc[t] - v;
        cur[t] = excl;
        int node = k * BUKSZ + t;
        if (node < NN) {
            row_beg[node] = base + excl;
            row_deg[node] = v;
            float di = rsqrtf((float)v + 1.0f);
            dinv[node] = di;
            float4 xv = x[node];
            xs[node] = make_float4(xv.x * di, xv.y * di, xv.z * di, xv.w * di);
        }
    }
    __syncthreads();
    for (int i = t; i < len; i += 512) {
        unsigned int pv = ebuf[i];
        int pos = atomicAdd(&cur[pv >> 17], 1);
        edges2[base + pos] = pv & 0x1FFFFu;
    }
}

// ---------------- layer 1 FUSED: wave-per-node gather + W1 GEMM -> fp16 h1 ----------------

__global__ __launch_bounds__(256) void g1f_k(
        const float4* __restrict__ xs, const unsigned int* __restrict__ csr,
        const int* __restrict__ row_beg, const int* __restrict__ row_deg,
        const float* __restrict__ dinv, const float* __restrict__ W1,
        const float* __restrict__ b1, __half* __restrict__ h1) {
    int wid = (blockIdx.x * blockDim.x + threadIdx.x) >> 6;
    int lane = threadIdx.x & 63;
    if (wid >= NN) return;
    int beg = row_beg[wid], deg = row_deg[wid];
    float sx = 0.f, sy = 0.f, sz = 0.f, sw = 0.f;
    for (int e = beg + lane; e < beg + deg; e += 64) {
        float4 w = xs[csr[e]];
        sx += w.x; sy += w.y; sz += w.z; sw += w.w;
    }
#pragma unroll
    for (int o = 1; o < 64; o <<= 1) {
        sx += __shfl_xor(sx, o);
        sy += __shfl_xor(sy, o);
        sz += __shfl_xor(sz, o);
        sw += __shfl_xor(sw, o);
    }
    float di = dinv[wid];
    float4 self = xs[wid];
    float ax = (sx + self.x) * di;
    float ay = (sy + self.y) * di;
    float az = (sz + self.z) * di;
    float aw = (sw + self.w) * di;
    float v = ax * W1[lane] + ay * W1[64 + lane] + az * W1[128 + lane] + aw * W1[192 + lane] + b1[lane];
    v = fmaxf(v, 0.f) * di;
    h1[(size_t)wid * HD + lane] = __float2half_rn(v);
}

// ---------------- layer 2 gather: wave per node; 16B/lane loads (4 rows/instr) ----------------

union H8 { int4 i4; __half2 h2[4]; };

__global__ __launch_bounds__(256) void gather2_k(
        const __half* __restrict__ h1, const unsigned int* __restrict__ csr,
        const int* __restrict__ row_beg, const int* __restrict__ row_deg,
        __half* __restrict__ a2h) {
    __shared__ int sidx[4][64];          // per-wave index slice (wave-private)
    int wv = threadIdx.x >> 6;
    int wid = (blockIdx.x * blockDim.x + threadIdx.x) >> 6;
    int lane = threadIdx.x & 63;
    if (wid >= NN) return;
    int half = lane >> 5;
    int g = (lane >> 3) & 3;
    int sub = lane & 7;
    int hg = half * 4 + g;               // edge slot 0..7 within an 8-edge block
    int beg = row_beg[wid], deg = row_deg[wid];
    float accx[4] = {0.f, 0.f, 0.f, 0.f};
    float accy[4] = {0.f, 0.f, 0.f, 0.f};
    int done = 0;
    while (done < deg) {
        int chunk = deg - done;
        if (chunk > 64) chunk = 64;
        if (lane < chunk) sidx[wv][lane] = (int)csr[beg + done + lane];  // 1 coalesced load
        int kb = 0;
        for (; kb + 31 < chunk; kb += 32) {
            int e0 = sidx[wv][kb + hg];
            int e1 = sidx[wv][kb + hg + 8];
            int e2 = sidx[wv][kb + hg + 16];
            int e3 = sidx[wv][kb + hg + 24];
            H8 r0, r1, r2, r3;
            r0.i4 = *(const int4*)(h1 + (size_t)e0 * HD + sub * 8);
            r1.i4 = *(const int4*)(h1 + (size_t)e1 * HD + sub * 8);
            r2.i4 = *(const int4*)(h1 + (size_t)e2 * HD + sub * 8);
            r3.i4 = *(const int4*)(h1 + (size_t)e3 * HD + sub * 8);
#pragma unroll
            for (int j = 0; j < 4; ++j) {
                float2 f0 = __half22float2(r0.h2[j]);
                float2 f1 = __half22float2(r1.h2[j]);
                float2 f2 = __half22float2(r2.h2[j]);
                float2 f3 = __half22float2(r3.h2[j]);
                accx[j] += (f0.x + f1.x) + (f2.x + f3.x);
                accy[j] += (f0.y + f1.y) + (f2.y + f3.y);
            }
        }
        for (; kb + 7 < chunk; kb += 8) {
            int e0 = sidx[wv][kb + hg];
            H8 r0;
            r0.i4 = *(const int4*)(h1 + (size_t)e0 * HD + sub * 8);
#pragma unroll
            for (int j = 0; j < 4; ++j) {
                float2 f0 = __half22float2(r0.h2[j]);
                accx[j] += f0.x;
                accy[j] += f0.y;
            }
        }
        if (kb < chunk) {
            int e = kb + hg;
            if (e < chunk) {
                int e0 = sidx[wv][e];
                H8 r0;
                r0.i4 = *(const int4*)(h1 + (size_t)e0 * HD + sub * 8);
#pragma unroll
                for (int j = 0; j < 4; ++j) {
                    float2 f0 = __half22float2(r0.h2[j]);
                    accx[j] += f0.x;
                    accy[j] += f0.y;
                }
            }
        }
        done += chunk;
    }
#pragma unroll
    for (int j = 0; j < 4; ++j) {
        accx[j] += __shfl_xor(accx[j], 8);
        accy[j] += __shfl_xor(accy[j], 8);
        accx[j] += __shfl_xor(accx[j], 16);
        accy[j] += __shfl_xor(accy[j], 16);
        accx[j] += __shfl_xor(accx[j], 32);
        accy[j] += __shfl_xor(accy[j], 32);
    }
    if (half == 0 && g == 0) {               // 8 lanes write the 128B row
        H8 sv, o;
        sv.i4 = *(const int4*)(h1 + (size_t)wid * HD + sub * 8);
#pragma unroll
        for (int j = 0; j < 4; ++j) {
            float2 fs = __half22float2(sv.h2[j]);
            o.h2[j] = __floats2half2_rn(accx[j] + fs.x, accy[j] + fs.y);
        }
        ((int4*)a2h)[(size_t)wid * 8 + sub] = o.i4;
    }
}

// ---------------- combine2 + pool: register GEMM, wave = 8 nodes, no LDS/barriers ----------------
// s[i](lane) = sum_k a2[node_i][k] * W2[k][lane]; a2[node][k] lives in lane k's a[i].
// readlane(a[i], k) with compile-time k: exec-independent broadcast -> SGPR FMA operand.

__global__ __launch_bounds__(512) void combine2_pool_k(
        const __half* __restrict__ a2h, const float* __restrict__ W2,
        const float* __restrict__ b2, const float* __restrict__ dinv,
        const int* __restrict__ batch, float* __restrict__ pool) {
    int tid = threadIdx.x;
    int wave = tid >> 6, lane = tid & 63;
    int base = blockIdx.x * 64 + wave * 8;   // first node of this wave
    // W2 column for this lane (L1/L2-hit, coalesced across lanes)
    float wcol[64];
#pragma unroll
    for (int k = 0; k < 64; ++k) wcol[k] = W2[k * HD + lane];
    float bv = b2[lane];
    // per-lane: feature `lane` of this wave's 8 nodes
    float a[8];
#pragma unroll
    for (int i = 0; i < 8; ++i) {
        int node = base + i;
        a[i] = (node < NN) ? __half2float(a2h[(size_t)node * HD + lane]) : 0.f;
    }
    float s[8] = {0.f, 0.f, 0.f, 0.f, 0.f, 0.f, 0.f, 0.f};
#pragma unroll
    for (int k = 0; k < 64; ++k) {
        float w = wcol[k];
#pragma unroll
        for (int i = 0; i < 8; ++i) {
            float av = __int_as_float(__builtin_amdgcn_readlane(__float_as_int(a[i]), k));
            s[i] = fmaf(av, w, s[i]);
        }
    }
    // relu + bias + batch-sorted flush from registers (per-wave, no barriers)
    int g = -1;
    float acc = 0.f;
#pragma unroll
    for (int i = 0; i < 8; ++i) {
        int node = base + i;
        if (node >= NN) break;
        float v = fmaxf(fmaf(dinv[node], s[i], bv), 0.f);
        int bg = batch[node];
        if (bg != g) {
            if (g >= 0) atomicAdd(&pool[g * HD + lane], acc);
            acc = 0.f; g = bg;
        }
        acc += v;
    }
    if (g >= 0) atomicAdd(&pool[g * HD + lane], acc);
}

__device__ __forceinline__ int lb_dev(const int* __restrict__ b, int n, int key) {
    int lo = 0, hi = n;
    while (lo < hi) {
        int mid = (lo + hi) >> 1;
        if (b[mid] < key) lo = mid + 1; else hi = mid;
    }
    return lo;
}

__global__ void final_k(const float* __restrict__ pool, const int* __restrict__ batch,
                        const float* __restrict__ Wlin, const float* __restrict__ blin,
                        float* __restrict__ out) {
    int g = blockIdx.x;
    int lane = threadIdx.x;
    int lo = lb_dev(batch, NN, g);
    int hi = lb_dev(batch, NN, g + 1);
    float cnt = (float)(hi - lo);
    float v = pool[g * HD + lane] * Wlin[lane];
#pragma unroll
    for (int off = 32; off > 0; off >>= 1) v += __shfl_down(v, off);
    if (lane == 0) out[g] = v / fmaxf(cnt, 1.0f) + blin[0];
}

// ---------------- launch ----------------

extern "C" void kernel_launch(void* const* d_in, const int* in_sizes, int n_in,
                              void* d_out, int out_size, void* d_ws, size_t ws_size,
                              hipStream_t stream) {
    const float* x    = (const float*)d_in[0];
    const int*   ei   = (const int*)d_in[1];
    const int*   bat  = (const int*)d_in[2];
    const float* W1   = (const float*)d_in[3];
    const float* b1   = (const float*)d_in[4];
    const float* W2   = (const float*)d_in[5];
    const float* b2   = (const float*)d_in[6];
    const float* Wlin = (const float*)d_in[7];
    const float* blin = (const float*)d_in[8];
    float* out = (float*)d_out;

    const int* src = ei;
    const int* dst = ei + NE;

    char* ws = (char*)d_ws;
    size_t off = 0;
    auto alloc = [&](size_t bytes) {
        char* p = ws + off;
        off += (bytes + 255) & ~(size_t)255;
        return p;
    };
    int*   bcur    = (int*)  alloc((NBUK + 1) * sizeof(int));
    int*   row_beg = (int*)  alloc(NN * sizeof(int));
    int*   row_deg = (int*)  alloc(NN * sizeof(int));
    float* dinv    = (float*)alloc(NN * sizeof(float));
    unsigned int* edges2 = (unsigned int*)alloc((size_t)NBUK * CAP * sizeof(unsigned int)); // 14.4 MB
    float4* xs     = (float4*)alloc((size_t)NN * sizeof(float4));
    __half* h1     = (__half*)alloc((size_t)NN * HD * sizeof(__half));
    __half* a2h    = (__half*)alloc((size_t)NN * HD * sizeof(__half));
    float* pool    = (float*)alloc((size_t)NG * HD * sizeof(float));
    (void)ws_size; (void)n_in; (void)in_sizes; (void)out_size;

    const int BLK = 256;
    const int gW = (NN * 64 + BLK - 1) / BLK;   // one wave per node

    // build: bucket runs -> in-place fine sort
    init_k<<<(NBUK + 1 + 255) / 256, 256, 0, stream>>>(bcur);
    stageA_k<<<NB, 512, 0, stream>>>(src, dst, bcur, edges2);
    build1_k<<<NBUK, 512, 0, stream>>>(bcur, (const float4*)x, edges2,
                                       row_beg, row_deg, dinv, xs);

    // layer 1 fused: gather + W1 GEMM -> fp16 h1
    g1f_k<<<gW, BLK, 0, stream>>>(xs, edges2, row_beg, row_deg, dinv, W1, b1, h1);

    // layer 2: wide-load gather (4 rows per VMEM instr) -> fp16 a2
    gather2_k<<<gW, BLK, 0, stream>>>(h1, edges2, row_beg, row_deg, a2h);

    // combine + pool + readout (register GEMM, 64 nodes per block)
    hipMemsetAsync(pool, 0, (size_t)NG * HD * sizeof(float), stream);
    combine2_pool_k<<<(NN + 63) / 64, 512, 0, stream>>>(a2h, W2, b2, dinv, bat, pool);
    final_k<<<NG, 64, 0, stream>>>(pool, bat, Wlin, blin, out);
}

// Round 17
// 205.813 us; speedup vs baseline: 1.0057x; 1.0057x over previous
//
#include <hip/hip_runtime.h>
#include <hip/hip_fp16.h>

#define NN 100000
#define NE 3200000
#define NG 2048
#define HD 64
#define BUKSZ 256         // nodes per bucket
#define NBUK 391          // ceil(NN / BUKSZ)
#define NB 512            // stage blocks
#define CHUNK 6250        // NE / NB exactly
#define CAP 9216          // padded edge capacity per bucket (mean 8192, sigma ~90)

// NOTE: int LDS atomics only (native ds ops). Float LDS atomicAdd is a CAS
// loop on this target (R8: 204.8M of them = 1342us) -- never use it.
// NOTE2 (R9): latency-bound gathers want max independent waves; do not make
// one wave process multiple nodes behind a block barrier.
// NOTE3 (R11): shfl with divergent srcLane under half-divergent loop bounds is
// undefined (reads exec-masked lanes). readlane with compile-time lane is safe
// (R16 passed correctness).
// NOTE4 (R15): gather was VMEM-issue-bound at 4B/lane loads; 16B/lane loads
// cover 4 rows per instruction (4x fewer VMEM instrs).
// NOTE5 (R16): a 64-float per-thread array SPILLS TO SCRATCH (VGPR=44 < 80
// needed) -> 205 MB scratch traffic = 60us. Stage W in chunks of <=16.

// ---------------- init per-bucket cursors (absolute) ----------------

__global__ void init_k(int* __restrict__ bcur) {
    int t = blockIdx.x * blockDim.x + threadIdx.x;
    if (t <= NBUK) bcur[t] = t * CAP;
}

// ---------------- pass 1: block-local bucket sort -> padded bucket runs ----------------
// packed value: (dst & 255) << 17 | src   (src < 2^17)

__global__ __launch_bounds__(512) void stageA_k(
        const int* __restrict__ src, const int* __restrict__ dst,
        int* __restrict__ bcur, unsigned int* __restrict__ edges2) {
    __shared__ int hist[NBUK];
    __shared__ int exb[NBUK + 1];
    __shared__ int cur[NBUK];
    __shared__ int obase[NBUK];
    __shared__ int sc[512];
    __shared__ unsigned int svals[CHUNK];
    __shared__ unsigned short sbuk[CHUNK];   // bucket id per sorted slot
    int b = blockIdx.x, t = threadIdx.x;
    int base = b * CHUNK;
    for (int i = t; i < NBUK; i += 512) hist[i] = 0;
    __syncthreads();
    for (int i = t; i < CHUNK; i += 512)
        atomicAdd(&hist[dst[base + i] >> 8], 1);
    __syncthreads();
    int v = (t < NBUK) ? hist[t] : 0;
    sc[t] = v;
    __syncthreads();
    for (int o = 1; o < 512; o <<= 1) {
        int u = (t >= o) ? sc[t - o] : 0;
        __syncthreads();
        sc[t] += u;
        __syncthreads();
    }
    if (t < NBUK) {
        int excl = sc[t] - v;
        exb[t] = excl;
        cur[t] = excl;
        obase[t] = v ? atomicAdd(&bcur[t], v) : 0;
    }
    if (t == 0) exb[NBUK] = CHUNK;
    __syncthreads();
    for (int i = t; i < CHUNK; i += 512) {
        int d = dst[base + i];
        int s = src[base + i];
        int bk = d >> 8;
        int pos = atomicAdd(&cur[bk], 1);
        svals[pos] = ((unsigned int)(d & 255) << 17) | (unsigned int)s;
        sbuk[pos] = (unsigned short)bk;
    }
    __syncthreads();
    for (int i = t; i < CHUNK; i += 512) {
        int lo = (int)sbuk[i];
        edges2[obase[lo] + (i - exb[lo])] = svals[i];
    }
}

// ---------------- pass 2: per-bucket fine sort (in-place) + row info + dinv + xs ----------------

__global__ __launch_bounds__(512) void build1_k(
        const int* __restrict__ bcur, const float4* __restrict__ x,
        unsigned int* __restrict__ edges2, int* __restrict__ row_beg,
        int* __restrict__ row_deg, float* __restrict__ dinv,
        float4* __restrict__ xs) {
    __shared__ unsigned int ebuf[CAP];   // 36 KB
    __shared__ int deg[BUKSZ];
    __shared__ int sc[BUKSZ];
    __shared__ int cur[BUKSZ];
    int k = blockIdx.x, t = threadIdx.x;
    int base = k * CAP;
    int len = bcur[k] - base;
    if (t < BUKSZ) deg[t] = 0;
    __syncthreads();
    for (int i = t; i < len; i += 512) {
        unsigned int pv = edges2[base + i];
        ebuf[i] = pv;
        atomicAdd(&deg[pv >> 17], 1);
    }
    __syncthreads();
    int v = 0;
    if (t < BUKSZ) { v = deg[t]; sc[t] = v; }
    __syncthreads();
    for (int o = 1; o < BUKSZ; o <<= 1) {
        int u = 0;
        if (t < BUKSZ && t >= o) u = sc[t - o];
        __syncthreads();
        if (t < BUKSZ && t >= o) sc[t] += u;
        __syncthreads();
    }
    if (t < BUKSZ) {
        int excl = sc[t] - v;
        cur[t] = excl;
        int node = k * BUKSZ + t;
        if (node < NN) {
            row_beg[node] = base + excl;
            row_deg[node] = v;
            float di = rsqrtf((float)v + 1.0f);
            dinv[node] = di;
            float4 xv = x[node];
            xs[node] = make_float4(xv.x * di, xv.y * di, xv.z * di, xv.w * di);
        }
    }
    __syncthreads();
    for (int i = t; i < len; i += 512) {
        unsigned int pv = ebuf[i];
        int pos = atomicAdd(&cur[pv >> 17], 1);
        edges2[base + pos] = pv & 0x1FFFFu;
    }
}

// ---------------- layer 1 FUSED: wave-per-node gather + W1 GEMM -> fp16 h1 ----------------

__global__ __launch_bounds__(256) void g1f_k(
        const float4* __restrict__ xs, const unsigned int* __restrict__ csr,
        const int* __restrict__ row_beg, const int* __restrict__ row_deg,
        const float* __restrict__ dinv, const float* __restrict__ W1,
        const float* __restrict__ b1, __half* __restrict__ h1) {
    int wid = (blockIdx.x * blockDim.x + threadIdx.x) >> 6;
    int lane = threadIdx.x & 63;
    if (wid >= NN) return;
    int beg = row_beg[wid], deg = row_deg[wid];
    float sx = 0.f, sy = 0.f, sz = 0.f, sw = 0.f;
    for (int e = beg + lane; e < beg + deg; e += 64) {
        float4 w = xs[csr[e]];
        sx += w.x; sy += w.y; sz += w.z; sw += w.w;
    }
#pragma unroll
    for (int o = 1; o < 64; o <<= 1) {
        sx += __shfl_xor(sx, o);
        sy += __shfl_xor(sy, o);
        sz += __shfl_xor(sz, o);
        sw += __shfl_xor(sw, o);
    }
    float di = dinv[wid];
    float4 self = xs[wid];
    float ax = (sx + self.x) * di;
    float ay = (sy + self.y) * di;
    float az = (sz + self.z) * di;
    float aw = (sw + self.w) * di;
    float v = ax * W1[lane] + ay * W1[64 + lane] + az * W1[128 + lane] + aw * W1[192 + lane] + b1[lane];
    v = fmaxf(v, 0.f) * di;
    h1[(size_t)wid * HD + lane] = __float2half_rn(v);
}

// ---------------- layer 2 gather: wave per node; 16B/lane loads (4 rows/instr) ----------------

union H8 { int4 i4; __half2 h2[4]; };

__global__ __launch_bounds__(256) void gather2_k(
        const __half* __restrict__ h1, const unsigned int* __restrict__ csr,
        const int* __restrict__ row_beg, const int* __restrict__ row_deg,
        __half* __restrict__ a2h) {
    __shared__ int sidx[4][64];          // per-wave index slice (wave-private)
    int wv = threadIdx.x >> 6;
    int wid = (blockIdx.x * blockDim.x + threadIdx.x) >> 6;
    int lane = threadIdx.x & 63;
    if (wid >= NN) return;
    int half = lane >> 5;
    int g = (lane >> 3) & 3;
    int sub = lane & 7;
    int hg = half * 4 + g;               // edge slot 0..7 within an 8-edge block
    int beg = row_beg[wid], deg = row_deg[wid];
    float accx[4] = {0.f, 0.f, 0.f, 0.f};
    float accy[4] = {0.f, 0.f, 0.f, 0.f};
    int done = 0;
    while (done < deg) {
        int chunk = deg - done;
        if (chunk > 64) chunk = 64;
        if (lane < chunk) sidx[wv][lane] = (int)csr[beg + done + lane];  // 1 coalesced load
        int kb = 0;
        for (; kb + 31 < chunk; kb += 32) {
            int e0 = sidx[wv][kb + hg];
            int e1 = sidx[wv][kb + hg + 8];
            int e2 = sidx[wv][kb + hg + 16];
            int e3 = sidx[wv][kb + hg + 24];
            H8 r0, r1, r2, r3;
            r0.i4 = *(const int4*)(h1 + (size_t)e0 * HD + sub * 8);
            r1.i4 = *(const int4*)(h1 + (size_t)e1 * HD + sub * 8);
            r2.i4 = *(const int4*)(h1 + (size_t)e2 * HD + sub * 8);
            r3.i4 = *(const int4*)(h1 + (size_t)e3 * HD + sub * 8);
#pragma unroll
            for (int j = 0; j < 4; ++j) {
                float2 f0 = __half22float2(r0.h2[j]);
                float2 f1 = __half22float2(r1.h2[j]);
                float2 f2 = __half22float2(r2.h2[j]);
                float2 f3 = __half22float2(r3.h2[j]);
                accx[j] += (f0.x + f1.x) + (f2.x + f3.x);
                accy[j] += (f0.y + f1.y) + (f2.y + f3.y);
            }
        }
        for (; kb + 7 < chunk; kb += 8) {
            int e0 = sidx[wv][kb + hg];
            H8 r0;
            r0.i4 = *(const int4*)(h1 + (size_t)e0 * HD + sub * 8);
#pragma unroll
            for (int j = 0; j < 4; ++j) {
                float2 f0 = __half22float2(r0.h2[j]);
                accx[j] += f0.x;
                accy[j] += f0.y;
            }
        }
        if (kb < chunk) {
            int e = kb + hg;
            if (e < chunk) {
                int e0 = sidx[wv][e];
                H8 r0;
                r0.i4 = *(const int4*)(h1 + (size_t)e0 * HD + sub * 8);
#pragma unroll
                for (int j = 0; j < 4; ++j) {
                    float2 f0 = __half22float2(r0.h2[j]);
                    accx[j] += f0.x;
                    accy[j] += f0.y;
                }
            }
        }
        done += chunk;
    }
#pragma unroll
    for (int j = 0; j < 4; ++j) {
        accx[j] += __shfl_xor(accx[j], 8);
        accy[j] += __shfl_xor(accy[j], 8);
        accx[j] += __shfl_xor(accx[j], 16);
        accy[j] += __shfl_xor(accy[j], 16);
        accx[j] += __shfl_xor(accx[j], 32);
        accy[j] += __shfl_xor(accy[j], 32);
    }
    if (half == 0 && g == 0) {               // 8 lanes write the 128B row
        H8 sv, o;
        sv.i4 = *(const int4*)(h1 + (size_t)wid * HD + sub * 8);
#pragma unroll
        for (int j = 0; j < 4; ++j) {
            float2 fs = __half22float2(sv.h2[j]);
            o.h2[j] = __floats2half2_rn(accx[j] + fs.x, accy[j] + fs.y);
        }
        ((int4*)a2h)[(size_t)wid * 8 + sub] = o.i4;
    }
}

// ---------------- combine2 + pool: register GEMM, wave = 8 nodes, no LDS/scratch ----------------
// s[i](lane) = sum_k a2[node_i][k] * W2[k][lane]; a2[node][k] lives in lane k's a[i].
// readlane(a[i], k) with compile-time k: exec-independent broadcast (R16-verified).
// W2 staged in 16-element register chunks -- NEVER a 64-wide array (R16 spill).

__global__ __launch_bounds__(512) void combine2_pool_k(
        const __half* __restrict__ a2h, const float* __restrict__ W2,
        const float* __restrict__ b2, const float* __restrict__ dinv,
        const int* __restrict__ batch, float* __restrict__ pool) {
    int tid = threadIdx.x;
    int wave = tid >> 6, lane = tid & 63;
    int base = blockIdx.x * 64 + wave * 8;   // first node of this wave
    float bv = b2[lane];
    // per-lane: feature `lane` of this wave's 8 nodes
    float a[8];
#pragma unroll
    for (int i = 0; i < 8; ++i) {
        int node = base + i;
        a[i] = (node < NN) ? __half2float(a2h[(size_t)node * HD + lane]) : 0.f;
    }
    float s[8] = {0.f, 0.f, 0.f, 0.f, 0.f, 0.f, 0.f, 0.f};
#pragma unroll
    for (int p = 0; p < 4; ++p) {            // 4 passes x 16 k: bounded register use
        float wc[16];
#pragma unroll
        for (int kk = 0; kk < 16; ++kk)
            wc[kk] = W2[(p * 16 + kk) * HD + lane];   // coalesced, L1-hit
#pragma unroll
        for (int kk = 0; kk < 16; ++kk) {
            float w = wc[kk];
#pragma unroll
            for (int i = 0; i < 8; ++i) {
                float av = __int_as_float(
                    __builtin_amdgcn_readlane(__float_as_int(a[i]), p * 16 + kk));
                s[i] = fmaf(av, w, s[i]);
            }
        }
    }
    // relu + bias + batch-sorted flush from registers (per-wave, no barriers)
    int g = -1;
    float acc = 0.f;
#pragma unroll
    for (int i = 0; i < 8; ++i) {
        int node = base + i;
        if (node >= NN) break;
        float v = fmaxf(fmaf(dinv[node], s[i], bv), 0.f);
        int bg = batch[node];
        if (bg != g) {
            if (g >= 0) atomicAdd(&pool[g * HD + lane], acc);
            acc = 0.f; g = bg;
        }
        acc += v;
    }
    if (g >= 0) atomicAdd(&pool[g * HD + lane], acc);
}

__device__ __forceinline__ int lb_dev(const int* __restrict__ b, int n, int key) {
    int lo = 0, hi = n;
    while (lo < hi) {
        int mid = (lo + hi) >> 1;
        if (b[mid] < key) lo = mid + 1; else hi = mid;
    }
    return lo;
}

__global__ void final_k(const float* __restrict__ pool, const int* __restrict__ batch,
                        const float* __restrict__ Wlin, const float* __restrict__ blin,
                        float* __restrict__ out) {
    int g = blockIdx.x;
    int lane = threadIdx.x;
    int lo = lb_dev(batch, NN, g);
    int hi = lb_dev(batch, NN, g + 1);
    float cnt = (float)(hi - lo);
    float v = pool[g * HD + lane] * Wlin[lane];
#pragma unroll
    for (int off = 32; off > 0; off >>= 1) v += __shfl_down(v, off);
    if (lane == 0) out[g] = v / fmaxf(cnt, 1.0f) + blin[0];
}

// ---------------- launch ----------------

extern "C" void kernel_launch(void* const* d_in, const int* in_sizes, int n_in,
                              void* d_out, int out_size, void* d_ws, size_t ws_size,
                              hipStream_t stream) {
    const float* x    = (const float*)d_in[0];
    const int*   ei   = (const int*)d_in[1];
    const int*   bat  = (const int*)d_in[2];
    const float* W1   = (const float*)d_in[3];
    const float* b1   = (const float*)d_in[4];
    const float* W2   = (const float*)d_in[5];
    const float* b2   = (const float*)d_in[6];
    const float* Wlin = (const float*)d_in[7];
    const float* blin = (const float*)d_in[8];
    float* out = (float*)d_out;

    const int* src = ei;
    const int* dst = ei + NE;

    char* ws = (char*)d_ws;
    size_t off = 0;
    auto alloc = [&](size_t bytes) {
        char* p = ws + off;
        off += (bytes + 255) & ~(size_t)255;
        return p;
    };
    int*   bcur    = (int*)  alloc((NBUK + 1) * sizeof(int));
    int*   row_beg = (int*)  alloc(NN * sizeof(int));
    int*   row_deg = (int*)  alloc(NN * sizeof(int));
    float* dinv    = (float*)alloc(NN * sizeof(float));
    unsigned int* edges2 = (unsigned int*)alloc((size_t)NBUK * CAP * sizeof(unsigned int)); // 14.4 MB
    float4* xs     = (float4*)alloc((size_t)NN * sizeof(float4));
    __half* h1     = (__half*)alloc((size_t)NN * HD * sizeof(__half));
    __half* a2h    = (__half*)alloc((size_t)NN * HD * sizeof(__half));
    float* pool    = (float*)alloc((size_t)NG * HD * sizeof(float));
    (void)ws_size; (void)n_in; (void)in_sizes; (void)out_size;

    const int BLK = 256;
    const int gW = (NN * 64 + BLK - 1) / BLK;   // one wave per node

    // build: bucket runs -> in-place fine sort
    init_k<<<(NBUK + 1 + 255) / 256, 256, 0, stream>>>(bcur);
    stageA_k<<<NB, 512, 0, stream>>>(src, dst, bcur, edges2);
    build1_k<<<NBUK, 512, 0, stream>>>(bcur, (const float4*)x, edges2,
                                       row_beg, row_deg, dinv, xs);

    // layer 1 fused: gather + W1 GEMM -> fp16 h1
    g1f_k<<<gW, BLK, 0, stream>>>(xs, edges2, row_beg, row_deg, dinv, W1, b1, h1);

    // layer 2: wide-load gather (4 rows per VMEM instr) -> fp16 a2
    gather2_k<<<gW, BLK, 0, stream>>>(h1, edges2, row_beg, row_deg, a2h);

    // combine + pool + readout (register GEMM, 64 nodes per block)
    hipMemsetAsync(pool, 0, (size_t)NG * HD * sizeof(float), stream);
    combine2_pool_k<<<(NN + 63) / 64, 512, 0, stream>>>(a2h, W2, b2, dinv, bat, pool);
    final_k<<<NG, 64, 0, stream>>>(pool, bat, Wlin, blin, out);
}

// Round 18
// 178.189 us; speedup vs baseline: 1.1616x; 1.1550x over previous
//
#include <hip/hip_runtime.h>
#include <hip/hip_fp16.h>

#define NN 100000
#define NE 3200000
#define NG 2048
#define HD 64
#define BUKSZ 256         // nodes per bucket
#define NBUK 391          // ceil(NN / BUKSZ)
#define NB 512            // stage blocks
#define CHUNK 6250        // NE / NB exactly
#define CAP 9216          // padded edge capacity per bucket

// NOTE: int LDS atomics only. Float LDS atomicAdd is a CAS loop (R8: 1342us).
// NOTE2 (R9): latency-bound gathers want max independent waves.
// NOTE3 (R11): shfl with divergent srcLane under divergent bounds is undefined.
// NOTE4 (R15): 16B/lane loads: 4 rows per VMEM instr.
// NOTE5 (R16): >16-float per-thread arrays spill to scratch (205MB = 60us).
// NOTE6 (R17): readlane-GEMM is VALU-issue-bound (1024 ops/wave = 60us);
// use MFMA (8 ops/wave). k-permutation errors cancel if A,B share k-mapping.

typedef __attribute__((ext_vector_type(8))) _Float16 f16x8;
typedef __attribute__((ext_vector_type(4))) float f32x4;
union I4H8 { int4 i4; f16x8 h8; };

// ---------------- init per-bucket cursors (absolute) ----------------

__global__ void init_k(int* __restrict__ bcur) {
    int t = blockIdx.x * blockDim.x + threadIdx.x;
    if (t <= NBUK) bcur[t] = t * CAP;
}

// ---------------- W2 -> transposed fp16 (W2t[n][k]) ----------------

__global__ void w2t_k(const float* __restrict__ W2, _Float16* __restrict__ W2t) {
    int t = blockIdx.x * blockDim.x + threadIdx.x;
    if (t < HD * HD) {
        int n = t >> 6, k = t & 63;
        W2t[n * HD + k] = (_Float16)W2[k * HD + n];
    }
}

// ---------------- pass 1: block-local bucket sort -> padded bucket runs ----------------
// packed value: (dst & 255) << 17 | src   (src < 2^17)

__global__ __launch_bounds__(512) void stageA_k(
        const int* __restrict__ src, const int* __restrict__ dst,
        int* __restrict__ bcur, unsigned int* __restrict__ edges2) {
    __shared__ int hist[NBUK];
    __shared__ int exb[NBUK + 1];
    __shared__ int cur[NBUK];
    __shared__ int obase[NBUK];
    __shared__ int sc[512];
    __shared__ unsigned int svals[CHUNK];
    __shared__ unsigned short sbuk[CHUNK];   // bucket id per sorted slot
    int b = blockIdx.x, t = threadIdx.x;
    int base = b * CHUNK;
    for (int i = t; i < NBUK; i += 512) hist[i] = 0;
    __syncthreads();
    for (int i = t; i < CHUNK; i += 512)
        atomicAdd(&hist[dst[base + i] >> 8], 1);
    __syncthreads();
    int v = (t < NBUK) ? hist[t] : 0;
    sc[t] = v;
    __syncthreads();
    for (int o = 1; o < 512; o <<= 1) {
        int u = (t >= o) ? sc[t - o] : 0;
        __syncthreads();
        sc[t] += u;
        __syncthreads();
    }
    if (t < NBUK) {
        int excl = sc[t] - v;
        exb[t] = excl;
        cur[t] = excl;
        obase[t] = v ? atomicAdd(&bcur[t], v) : 0;
    }
    if (t == 0) exb[NBUK] = CHUNK;
    __syncthreads();
    for (int i = t; i < CHUNK; i += 512) {
        int d = dst[base + i];
        int s = src[base + i];
        int bk = d >> 8;
        int pos = atomicAdd(&cur[bk], 1);
        svals[pos] = ((unsigned int)(d & 255) << 17) | (unsigned int)s;
        sbuk[pos] = (unsigned short)bk;
    }
    __syncthreads();
    for (int i = t; i < CHUNK; i += 512) {
        int lo = (int)sbuk[i];
        edges2[obase[lo] + (i - exb[lo])] = svals[i];
    }
}

// ---------------- pass 2: per-bucket fine sort (in-place) + row info + dinv + xs ----------------

__global__ __launch_bounds__(512) void build1_k(
        const int* __restrict__ bcur, const float4* __restrict__ x,
        unsigned int* __restrict__ edges2, int* __restrict__ row_beg,
        int* __restrict__ row_deg, float* __restrict__ dinv,
        float4* __restrict__ xs) {
    __shared__ unsigned int ebuf[CAP];   // 36 KB
    __shared__ int deg[BUKSZ];
    __shared__ int sc[BUKSZ];
    __shared__ int cur[BUKSZ];
    int k = blockIdx.x, t = threadIdx.x;
    int base = k * CAP;
    int len = bcur[k] - base;
    if (t < BUKSZ) deg[t] = 0;
    __syncthreads();
    for (int i = t; i < len; i += 512) {
        unsigned int pv = edges2[base + i];
        ebuf[i] = pv;
        atomicAdd(&deg[pv >> 17], 1);
    }
    __syncthreads();
    int v = 0;
    if (t < BUKSZ) { v = deg[t]; sc[t] = v; }
    __syncthreads();
    for (int o = 1; o < BUKSZ; o <<= 1) {
        int u = 0;
        if (t < BUKSZ && t >= o) u = sc[t - o];
        __syncthreads();
        if (t < BUKSZ && t >= o) sc[t] += u;
        __syncthreads();
    }
    if (t < BUKSZ) {
        int excl = sc[t] - v;
        cur[t] = excl;
        int node = k * BUKSZ + t;
        if (node < NN) {
            row_beg[node] = base + excl;
            row_deg[node] = v;
            float di = rsqrtf((float)v + 1.0f);
            dinv[node] = di;
            float4 xv = x[node];
            xs[node] = make_float4(xv.x * di, xv.y * di, xv.z * di, xv.w * di);
        }
    }
    __syncthreads();
    for (int i = t; i < len; i += 512) {
        unsigned int pv = ebuf[i];
        int pos = atomicAdd(&cur[pv >> 17], 1);
        edges2[base + pos] = pv & 0x1FFFFu;
    }
}

// ---------------- layer 1 FUSED: wave-per-node gather + W1 GEMM -> fp16 h1 ----------------

__global__ __launch_bounds__(256) void g1f_k(
        const float4* __restrict__ xs, const unsigned int* __restrict__ csr,
        const int* __restrict__ row_beg, const int* __restrict__ row_deg,
        const float* __restrict__ dinv, const float* __restrict__ W1,
        const float* __restrict__ b1, __half* __restrict__ h1) {
    int wid = (blockIdx.x * blockDim.x + threadIdx.x) >> 6;
    int lane = threadIdx.x & 63;
    if (wid >= NN) return;
    int beg = row_beg[wid], deg = row_deg[wid];
    float sx = 0.f, sy = 0.f, sz = 0.f, sw = 0.f;
    for (int e = beg + lane; e < beg + deg; e += 64) {
        float4 w = xs[csr[e]];
        sx += w.x; sy += w.y; sz += w.z; sw += w.w;
    }
#pragma unroll
    for (int o = 1; o < 64; o <<= 1) {
        sx += __shfl_xor(sx, o);
        sy += __shfl_xor(sy, o);
        sz += __shfl_xor(sz, o);
        sw += __shfl_xor(sw, o);
    }
    float di = dinv[wid];
    float4 self = xs[wid];
    float ax = (sx + self.x) * di;
    float ay = (sy + self.y) * di;
    float az = (sz + self.z) * di;
    float aw = (sw + self.w) * di;
    float v = ax * W1[lane] + ay * W1[64 + lane] + az * W1[128 + lane] + aw * W1[192 + lane] + b1[lane];
    v = fmaxf(v, 0.f) * di;
    h1[(size_t)wid * HD + lane] = __float2half_rn(v);
}

// ---------------- layer 2 gather: wave per node; 16B/lane loads (4 rows/instr) ----------------

union H8 { int4 i4; __half2 h2[4]; };

__global__ __launch_bounds__(256) void gather2_k(
        const __half* __restrict__ h1, const unsigned int* __restrict__ csr,
        const int* __restrict__ row_beg, const int* __restrict__ row_deg,
        __half* __restrict__ a2h) {
    __shared__ int sidx[4][64];          // per-wave index slice (wave-private)
    int wv = threadIdx.x >> 6;
    int wid = (blockIdx.x * blockDim.x + threadIdx.x) >> 6;
    int lane = threadIdx.x & 63;
    if (wid >= NN) return;
    int half = lane >> 5;
    int g = (lane >> 3) & 3;
    int sub = lane & 7;
    int hg = half * 4 + g;               // edge slot 0..7 within an 8-edge block
    int beg = row_beg[wid], deg = row_deg[wid];
    float accx[4] = {0.f, 0.f, 0.f, 0.f};
    float accy[4] = {0.f, 0.f, 0.f, 0.f};
    int done = 0;
    while (done < deg) {
        int chunk = deg - done;
        if (chunk > 64) chunk = 64;
        if (lane < chunk) sidx[wv][lane] = (int)csr[beg + done + lane];  // 1 coalesced load
        int kb = 0;
        for (; kb + 31 < chunk; kb += 32) {
            int e0 = sidx[wv][kb + hg];
            int e1 = sidx[wv][kb + hg + 8];
            int e2 = sidx[wv][kb + hg + 16];
            int e3 = sidx[wv][kb + hg + 24];
            H8 r0, r1, r2, r3;
            r0.i4 = *(const int4*)(h1 + (size_t)e0 * HD + sub * 8);
            r1.i4 = *(const int4*)(h1 + (size_t)e1 * HD + sub * 8);
            r2.i4 = *(const int4*)(h1 + (size_t)e2 * HD + sub * 8);
            r3.i4 = *(const int4*)(h1 + (size_t)e3 * HD + sub * 8);
#pragma unroll
            for (int j = 0; j < 4; ++j) {
                float2 f0 = __half22float2(r0.h2[j]);
                float2 f1 = __half22float2(r1.h2[j]);
                float2 f2 = __half22float2(r2.h2[j]);
                float2 f3 = __half22float2(r3.h2[j]);
                accx[j] += (f0.x + f1.x) + (f2.x + f3.x);
                accy[j] += (f0.y + f1.y) + (f2.y + f3.y);
            }
        }
        for (; kb + 7 < chunk; kb += 8) {
            int e0 = sidx[wv][kb + hg];
            H8 r0;
            r0.i4 = *(const int4*)(h1 + (size_t)e0 * HD + sub * 8);
#pragma unroll
            for (int j = 0; j < 4; ++j) {
                float2 f0 = __half22float2(r0.h2[j]);
                accx[j] += f0.x;
                accy[j] += f0.y;
            }
        }
        if (kb < chunk) {
            int e = kb + hg;
            if (e < chunk) {
                int e0 = sidx[wv][e];
                H8 r0;
                r0.i4 = *(const int4*)(h1 + (size_t)e0 * HD + sub * 8);
#pragma unroll
                for (int j = 0; j < 4; ++j) {
                    float2 f0 = __half22float2(r0.h2[j]);
                    accx[j] += f0.x;
                    accy[j] += f0.y;
                }
            }
        }
        done += chunk;
    }
#pragma unroll
    for (int j = 0; j < 4; ++j) {
        accx[j] += __shfl_xor(accx[j], 8);
        accy[j] += __shfl_xor(accy[j], 8);
        accx[j] += __shfl_xor(accx[j], 16);
        accy[j] += __shfl_xor(accy[j], 16);
        accx[j] += __shfl_xor(accx[j], 32);
        accy[j] += __shfl_xor(accy[j], 32);
    }
    if (half == 0 && g == 0) {               // 8 lanes write the 128B row
        H8 sv, o;
        sv.i4 = *(const int4*)(h1 + (size_t)wid * HD + sub * 8);
#pragma unroll
        for (int j = 0; j < 4; ++j) {
            float2 fs = __half22float2(sv.h2[j]);
            o.h2[j] = __floats2half2_rn(accx[j] + fs.x, accy[j] + fs.y);
        }
        ((int4*)a2h)[(size_t)wid * 8 + sub] = o.i4;
    }
}

// ---------------- combine2 + pool via MFMA: wave = 16 nodes, 8 mfma ----------------
// D[m][n] = sum_k a2[base+m][k] * W2[k][n]; A lane: m=lane&15, k=(lane>>4)*8+j.
// B from W2t[n][k]: n=lane&15, same k mapping -> one 16B load per fragment.
// C/D (guide-verified): col=lane&15 (n), row=(lane>>4)*4+reg (m).

__global__ __launch_bounds__(256) void c2mfma_k(
        const __half* __restrict__ a2h, const _Float16* __restrict__ W2t,
        const float* __restrict__ b2, const float* __restrict__ dinv,
        const int* __restrict__ batch, float* __restrict__ pool) {
    int tid = threadIdx.x;
    int wave = tid >> 6, lane = tid & 63;
    int base = blockIdx.x * 64 + wave * 16;
    int m = lane & 15, kb = lane >> 4;
    // B fragments: 8 x 16B loads from the 8KB L1-resident W2t
    f16x8 bfr[2][4];
#pragma unroll
    for (int kt = 0; kt < 2; ++kt)
#pragma unroll
        for (int nt = 0; nt < 4; ++nt) {
            I4H8 u;
            u.i4 = *(const int4*)(W2t + (nt * 16 + m) * HD + kt * 32 + kb * 8);
            bfr[kt][nt] = u.h8;
        }
    // A fragments: 2 x 16B loads (node rows)
    f16x8 afr[2];
    int anode = base + m;
#pragma unroll
    for (int kt = 0; kt < 2; ++kt) {
        I4H8 u;
        if (anode < NN)
            u.i4 = *(const int4*)(a2h + (size_t)anode * HD + kt * 32 + kb * 8);
        else
            u.i4 = make_int4(0, 0, 0, 0);
        afr[kt] = u.h8;
    }
    f32x4 acc[4] = {{0.f, 0.f, 0.f, 0.f}, {0.f, 0.f, 0.f, 0.f},
                    {0.f, 0.f, 0.f, 0.f}, {0.f, 0.f, 0.f, 0.f}};
#pragma unroll
    for (int kt = 0; kt < 2; ++kt)
#pragma unroll
        for (int nt = 0; nt < 4; ++nt)
            acc[nt] = __builtin_amdgcn_mfma_f32_16x16x32_f16(afr[kt], bfr[kt][nt], acc[nt], 0, 0, 0);
    // epilogue: my 4 rows are nodes base + kb*4 + r
    int r0 = base + kb * 4;
    float dv[4];
    int bg[4];
#pragma unroll
    for (int r = 0; r < 4; ++r) {
        int node = r0 + r;
        dv[r] = (node < NN) ? dinv[node] : 0.f;
        bg[r] = (node < NN) ? batch[node] : -1;
    }
#pragma unroll
    for (int nt = 0; nt < 4; ++nt) {
        int n = nt * 16 + m;
        float bv = b2[n];
        int g = -1;
        float accf = 0.f;
#pragma unroll
        for (int r = 0; r < 4; ++r) {
            if (bg[r] < 0) break;
            float v = fmaxf(fmaf(dv[r], acc[nt][r], bv), 0.f);
            if (bg[r] != g) {
                if (g >= 0) atomicAdd(&pool[g * HD + n], accf);
                accf = 0.f; g = bg[r];
            }
            accf += v;
        }
        if (g >= 0) atomicAdd(&pool[g * HD + n], accf);
    }
}

__device__ __forceinline__ int lb_dev(const int* __restrict__ b, int n, int key) {
    int lo = 0, hi = n;
    while (lo < hi) {
        int mid = (lo + hi) >> 1;
        if (b[mid] < key) lo = mid + 1; else hi = mid;
    }
    return lo;
}

__global__ void final_k(const float* __restrict__ pool, const int* __restrict__ batch,
                        const float* __restrict__ Wlin, const float* __restrict__ blin,
                        float* __restrict__ out) {
    int g = blockIdx.x;
    int lane = threadIdx.x;
    int lo = lb_dev(batch, NN, g);
    int hi = lb_dev(batch, NN, g + 1);
    float cnt = (float)(hi - lo);
    float v = pool[g * HD + lane] * Wlin[lane];
#pragma unroll
    for (int off = 32; off > 0; off >>= 1) v += __shfl_down(v, off);
    if (lane == 0) out[g] = v / fmaxf(cnt, 1.0f) + blin[0];
}

// ---------------- launch ----------------

extern "C" void kernel_launch(void* const* d_in, const int* in_sizes, int n_in,
                              void* d_out, int out_size, void* d_ws, size_t ws_size,
                              hipStream_t stream) {
    const float* x    = (const float*)d_in[0];
    const int*   ei   = (const int*)d_in[1];
    const int*   bat  = (const int*)d_in[2];
    const float* W1   = (const float*)d_in[3];
    const float* b1   = (const float*)d_in[4];
    const float* W2   = (const float*)d_in[5];
    const float* b2   = (const float*)d_in[6];
    const float* Wlin = (const float*)d_in[7];
    const float* blin = (const float*)d_in[8];
    float* out = (float*)d_out;

    const int* src = ei;
    const int* dst = ei + NE;

    char* ws = (char*)d_ws;
    size_t off = 0;
    auto alloc = [&](size_t bytes) {
        char* p = ws + off;
        off += (bytes + 255) & ~(size_t)255;
        return p;
    };
    int*   bcur    = (int*)  alloc((NBUK + 1) * sizeof(int));
    int*   row_beg = (int*)  alloc(NN * sizeof(int));
    int*   row_deg = (int*)  alloc(NN * sizeof(int));
    float* dinv    = (float*)alloc(NN * sizeof(float));
    unsigned int* edges2 = (unsigned int*)alloc((size_t)NBUK * CAP * sizeof(unsigned int)); // 14.4 MB
    float4* xs     = (float4*)alloc((size_t)NN * sizeof(float4));
    __half* h1     = (__half*)alloc((size_t)NN * HD * sizeof(__half));
    __half* a2h    = (__half*)alloc((size_t)NN * HD * sizeof(__half));
    _Float16* W2t  = (_Float16*)alloc(HD * HD * sizeof(_Float16));
    float* pool    = (float*)alloc((size_t)NG * HD * sizeof(float));
    (void)ws_size; (void)n_in; (void)in_sizes; (void)out_size;

    const int BLK = 256;
    const int gW = (NN * 64 + BLK - 1) / BLK;   // one wave per node

    // build: bucket runs -> in-place fine sort (+ W2 transpose/convert)
    init_k<<<(NBUK + 1 + 255) / 256, 256, 0, stream>>>(bcur);
    w2t_k<<<16, 256, 0, stream>>>(W2, W2t);
    stageA_k<<<NB, 512, 0, stream>>>(src, dst, bcur, edges2);
    build1_k<<<NBUK, 512, 0, stream>>>(bcur, (const float4*)x, edges2,
                                       row_beg, row_deg, dinv, xs);

    // layer 1 fused: gather + W1 GEMM -> fp16 h1
    g1f_k<<<gW, BLK, 0, stream>>>(xs, edges2, row_beg, row_deg, dinv, W1, b1, h1);

    // layer 2: wide-load gather (4 rows per VMEM instr) -> fp16 a2
    gather2_k<<<gW, BLK, 0, stream>>>(h1, edges2, row_beg, row_deg, a2h);

    // combine + pool + readout (MFMA GEMM, 64 nodes per block)
    hipMemsetAsync(pool, 0, (size_t)NG * HD * sizeof(float), stream);
    c2mfma_k<<<(NN + 63) / 64, 256, 0, stream>>>(a2h, W2t, b2, dinv, bat, pool);
    final_k<<<NG, 64, 0, stream>>>(pool, bat, Wlin, blin, out);
}

// Round 19
// 176.611 us; speedup vs baseline: 1.1720x; 1.0089x over previous
//
#include <hip/hip_runtime.h>
#include <hip/hip_fp16.h>

#define NN 100000
#define NE 3200000
#define NG 2048
#define HD 64
#define BUKSZ 256         // nodes per bucket
#define NBUK 391          // ceil(NN / BUKSZ)
#define NB 512            // stage blocks
#define CHUNK 6250        // NE / NB exactly
#define CAP 9216          // padded edge capacity per bucket

// NOTE: int LDS atomics only. Float LDS atomicAdd is a CAS loop (R8: 1342us).
// NOTE2 (R9): latency-bound gathers want max independent waves.
// NOTE3 (R11): shfl with divergent srcLane under divergent bounds is undefined.
// NOTE4 (R15): 16B/lane loads: 4 rows per VMEM instr.
// NOTE5 (R16): >16-float per-thread arrays spill to scratch (205MB = 60us).
// NOTE6 (R17): readlane-GEMM is VALU-issue-bound; MFMA = 8 ops/wave (R18: -28us).
// NOTE7 (R19): gather decode was cvt-heavy; packed fp16 accumulation
// (v_pk_add_f16 via __hadd2) removes all cvt from the inner loop.

typedef __attribute__((ext_vector_type(8))) _Float16 f16x8;
typedef __attribute__((ext_vector_type(4))) float f32x4;
union I4H8 { int4 i4; f16x8 h8; };

// ---------------- init per-bucket cursors (absolute) ----------------

__global__ void init_k(int* __restrict__ bcur) {
    int t = blockIdx.x * blockDim.x + threadIdx.x;
    if (t <= NBUK) bcur[t] = t * CAP;
}

// ---------------- W2 -> transposed fp16 (W2t[n][k]) ----------------

__global__ void w2t_k(const float* __restrict__ W2, _Float16* __restrict__ W2t) {
    int t = blockIdx.x * blockDim.x + threadIdx.x;
    if (t < HD * HD) {
        int n = t >> 6, k = t & 63;
        W2t[n * HD + k] = (_Float16)W2[k * HD + n];
    }
}

// ---------------- pass 1: block-local bucket sort -> padded bucket runs ----------------
// packed value: (dst & 255) << 17 | src   (src < 2^17)

__global__ __launch_bounds__(512) void stageA_k(
        const int* __restrict__ src, const int* __restrict__ dst,
        int* __restrict__ bcur, unsigned int* __restrict__ edges2) {
    __shared__ int hist[NBUK];
    __shared__ int exb[NBUK + 1];
    __shared__ int cur[NBUK];
    __shared__ int obase[NBUK];
    __shared__ int sc[512];
    __shared__ unsigned int svals[CHUNK];
    __shared__ unsigned short sbuk[CHUNK];   // bucket id per sorted slot
    int b = blockIdx.x, t = threadIdx.x;
    int base = b * CHUNK;
    for (int i = t; i < NBUK; i += 512) hist[i] = 0;
    __syncthreads();
    for (int i = t; i < CHUNK; i += 512)
        atomicAdd(&hist[dst[base + i] >> 8], 1);
    __syncthreads();
    int v = (t < NBUK) ? hist[t] : 0;
    sc[t] = v;
    __syncthreads();
    for (int o = 1; o < 512; o <<= 1) {
        int u = (t >= o) ? sc[t - o] : 0;
        __syncthreads();
        sc[t] += u;
        __syncthreads();
    }
    if (t < NBUK) {
        int excl = sc[t] - v;
        exb[t] = excl;
        cur[t] = excl;
        obase[t] = v ? atomicAdd(&bcur[t], v) : 0;
    }
    if (t == 0) exb[NBUK] = CHUNK;
    __syncthreads();
    for (int i = t; i < CHUNK; i += 512) {
        int d = dst[base + i];
        int s = src[base + i];
        int bk = d >> 8;
        int pos = atomicAdd(&cur[bk], 1);
        svals[pos] = ((unsigned int)(d & 255) << 17) | (unsigned int)s;
        sbuk[pos] = (unsigned short)bk;
    }
    __syncthreads();
    for (int i = t; i < CHUNK; i += 512) {
        int lo = (int)sbuk[i];
        edges2[obase[lo] + (i - exb[lo])] = svals[i];
    }
}

// ---------------- pass 2: per-bucket fine sort (in-place) + row info + dinv + xs ----------------

__global__ __launch_bounds__(512) void build1_k(
        const int* __restrict__ bcur, const float4* __restrict__ x,
        unsigned int* __restrict__ edges2, int* __restrict__ row_beg,
        int* __restrict__ row_deg, float* __restrict__ dinv,
        float4* __restrict__ xs) {
    __shared__ unsigned int ebuf[CAP];   // 36 KB
    __shared__ int deg[BUKSZ];
    __shared__ int sc[BUKSZ];
    __shared__ int cur[BUKSZ];
    int k = blockIdx.x, t = threadIdx.x;
    int base = k * CAP;
    int len = bcur[k] - base;
    if (t < BUKSZ) deg[t] = 0;
    __syncthreads();
    for (int i = t; i < len; i += 512) {
        unsigned int pv = edges2[base + i];
        ebuf[i] = pv;
        atomicAdd(&deg[pv >> 17], 1);
    }
    __syncthreads();
    int v = 0;
    if (t < BUKSZ) { v = deg[t]; sc[t] = v; }
    __syncthreads();
    for (int o = 1; o < BUKSZ; o <<= 1) {
        int u = 0;
        if (t < BUKSZ && t >= o) u = sc[t - o];
        __syncthreads();
        if (t < BUKSZ && t >= o) sc[t] += u;
        __syncthreads();
    }
    if (t < BUKSZ) {
        int excl = sc[t] - v;
        cur[t] = excl;
        int node = k * BUKSZ + t;
        if (node < NN) {
            row_beg[node] = base + excl;
            row_deg[node] = v;
            float di = rsqrtf((float)v + 1.0f);
            dinv[node] = di;
            float4 xv = x[node];
            xs[node] = make_float4(xv.x * di, xv.y * di, xv.z * di, xv.w * di);
        }
    }
    __syncthreads();
    for (int i = t; i < len; i += 512) {
        unsigned int pv = ebuf[i];
        int pos = atomicAdd(&cur[pv >> 17], 1);
        edges2[base + pos] = pv & 0x1FFFFu;
    }
}

// ---------------- layer 1 FUSED: wave-per-node gather + W1 GEMM -> fp16 h1 ----------------

__global__ __launch_bounds__(256) void g1f_k(
        const float4* __restrict__ xs, const unsigned int* __restrict__ csr,
        const int* __restrict__ row_beg, const int* __restrict__ row_deg,
        const float* __restrict__ dinv, const float* __restrict__ W1,
        const float* __restrict__ b1, __half* __restrict__ h1) {
    int wid = (blockIdx.x * blockDim.x + threadIdx.x) >> 6;
    int lane = threadIdx.x & 63;
    if (wid >= NN) return;
    int beg = row_beg[wid], deg = row_deg[wid];
    float sx = 0.f, sy = 0.f, sz = 0.f, sw = 0.f;
    for (int e = beg + lane; e < beg + deg; e += 64) {
        float4 w = xs[csr[e]];
        sx += w.x; sy += w.y; sz += w.z; sw += w.w;
    }
#pragma unroll
    for (int o = 1; o < 64; o <<= 1) {
        sx += __shfl_xor(sx, o);
        sy += __shfl_xor(sy, o);
        sz += __shfl_xor(sz, o);
        sw += __shfl_xor(sw, o);
    }
    float di = dinv[wid];
    float4 self = xs[wid];
    float ax = (sx + self.x) * di;
    float ay = (sy + self.y) * di;
    float az = (sz + self.z) * di;
    float aw = (sw + self.w) * di;
    float v = ax * W1[lane] + ay * W1[64 + lane] + az * W1[128 + lane] + aw * W1[192 + lane] + b1[lane];
    v = fmaxf(v, 0.f) * di;
    h1[(size_t)wid * HD + lane] = __float2half_rn(v);
}

// ---------------- layer 2 gather: wave per node; 16B/lane loads, fp16 packed accum ----------------

union H8 { int4 i4; __half2 h2[4]; };

__device__ __forceinline__ __half2 shfl_xor_h2(__half2 a, int m) {
    int v = *(int*)&a;
    int s = __shfl_xor(v, m);
    return *(__half2*)&s;
}

__global__ __launch_bounds__(256) void gather2_k(
        const __half* __restrict__ h1, const unsigned int* __restrict__ csr,
        const int* __restrict__ row_beg, const int* __restrict__ row_deg,
        __half* __restrict__ a2h) {
    __shared__ int sidx[4][64];          // per-wave index slice (wave-private)
    int wv = threadIdx.x >> 6;
    int wid = (blockIdx.x * blockDim.x + threadIdx.x) >> 6;
    int lane = threadIdx.x & 63;
    if (wid >= NN) return;
    int half = lane >> 5;
    int g = (lane >> 3) & 3;
    int sub = lane & 7;
    int hg = half * 4 + g;               // edge slot 0..7 within an 8-edge block
    int beg = row_beg[wid], deg = row_deg[wid];
    __half2 acc[4];
#pragma unroll
    for (int j = 0; j < 4; ++j) acc[j] = __half2half2(__float2half(0.f));
    int done = 0;
    while (done < deg) {
        int chunk = deg - done;
        if (chunk > 64) chunk = 64;
        if (lane < chunk) sidx[wv][lane] = (int)csr[beg + done + lane];  // 1 coalesced load
        int kb = 0;
        for (; kb + 31 < chunk; kb += 32) {      // 32 edges: 4 x 16B loads/lane
            int e0 = sidx[wv][kb + hg];
            int e1 = sidx[wv][kb + hg + 8];
            int e2 = sidx[wv][kb + hg + 16];
            int e3 = sidx[wv][kb + hg + 24];
            H8 r0, r1, r2, r3;
            r0.i4 = *(const int4*)(h1 + (size_t)e0 * HD + sub * 8);
            r1.i4 = *(const int4*)(h1 + (size_t)e1 * HD + sub * 8);
            r2.i4 = *(const int4*)(h1 + (size_t)e2 * HD + sub * 8);
            r3.i4 = *(const int4*)(h1 + (size_t)e3 * HD + sub * 8);
#pragma unroll
            for (int j = 0; j < 4; ++j) {
                acc[j] = __hadd2(acc[j], __hadd2(__hadd2(r0.h2[j], r1.h2[j]),
                                                 __hadd2(r2.h2[j], r3.h2[j])));
            }
        }
        for (; kb + 7 < chunk; kb += 8) {        // 8 edges: 1 load/lane
            int e0 = sidx[wv][kb + hg];
            H8 r0;
            r0.i4 = *(const int4*)(h1 + (size_t)e0 * HD + sub * 8);
#pragma unroll
            for (int j = 0; j < 4; ++j) acc[j] = __hadd2(acc[j], r0.h2[j]);
        }
        if (kb < chunk) {                        // tail <8: predicated per 8-lane group
            int e = kb + hg;
            if (e < chunk) {
                int e0 = sidx[wv][e];
                H8 r0;
                r0.i4 = *(const int4*)(h1 + (size_t)e0 * HD + sub * 8);
#pragma unroll
                for (int j = 0; j < 4; ++j) acc[j] = __hadd2(acc[j], r0.h2[j]);
            }
        }
        done += chunk;
    }
    // reduce across groups (xor 8,16) and halves (xor 32); uniform, all lanes active
#pragma unroll
    for (int j = 0; j < 4; ++j) {
        acc[j] = __hadd2(acc[j], shfl_xor_h2(acc[j], 8));
        acc[j] = __hadd2(acc[j], shfl_xor_h2(acc[j], 16));
        acc[j] = __hadd2(acc[j], shfl_xor_h2(acc[j], 32));
    }
    if (half == 0 && g == 0) {               // 8 lanes write the 128B row
        H8 sv, o;
        sv.i4 = *(const int4*)(h1 + (size_t)wid * HD + sub * 8);
#pragma unroll
        for (int j = 0; j < 4; ++j) o.h2[j] = __hadd2(acc[j], sv.h2[j]);
        ((int4*)a2h)[(size_t)wid * 8 + sub] = o.i4;
    }
}

// ---------------- combine2 + pool via MFMA: wave = 16 nodes, 8 mfma ----------------
// D[m][n] = sum_k a2[base+m][k] * W2[k][n]; A lane: m=lane&15, k=(lane>>4)*8+j.
// B from W2t[n][k]: n=lane&15, same k mapping. C/D: col=lane&15, row=(lane>>4)*4+reg.

__global__ __launch_bounds__(256) void c2mfma_k(
        const __half* __restrict__ a2h, const _Float16* __restrict__ W2t,
        const float* __restrict__ b2, const float* __restrict__ dinv,
        const int* __restrict__ batch, float* __restrict__ pool) {
    int tid = threadIdx.x;
    int wave = tid >> 6, lane = tid & 63;
    int base = blockIdx.x * 64 + wave * 16;
    int m = lane & 15, kb = lane >> 4;
    f16x8 bfr[2][4];
#pragma unroll
    for (int kt = 0; kt < 2; ++kt)
#pragma unroll
        for (int nt = 0; nt < 4; ++nt) {
            I4H8 u;
            u.i4 = *(const int4*)(W2t + (nt * 16 + m) * HD + kt * 32 + kb * 8);
            bfr[kt][nt] = u.h8;
        }
    f16x8 afr[2];
    int anode = base + m;
#pragma unroll
    for (int kt = 0; kt < 2; ++kt) {
        I4H8 u;
        if (anode < NN)
            u.i4 = *(const int4*)(a2h + (size_t)anode * HD + kt * 32 + kb * 8);
        else
            u.i4 = make_int4(0, 0, 0, 0);
        afr[kt] = u.h8;
    }
    f32x4 acc[4] = {{0.f, 0.f, 0.f, 0.f}, {0.f, 0.f, 0.f, 0.f},
                    {0.f, 0.f, 0.f, 0.f}, {0.f, 0.f, 0.f, 0.f}};
#pragma unroll
    for (int kt = 0; kt < 2; ++kt)
#pragma unroll
        for (int nt = 0; nt < 4; ++nt)
            acc[nt] = __builtin_amdgcn_mfma_f32_16x16x32_f16(afr[kt], bfr[kt][nt], acc[nt], 0, 0, 0);
    int r0 = base + kb * 4;
    float dv[4];
    int bg[4];
#pragma unroll
    for (int r = 0; r < 4; ++r) {
        int node = r0 + r;
        dv[r] = (node < NN) ? dinv[node] : 0.f;
        bg[r] = (node < NN) ? batch[node] : -1;
    }
#pragma unroll
    for (int nt = 0; nt < 4; ++nt) {
        int n = nt * 16 + m;
        float bv = b2[n];
        int g = -1;
        float accf = 0.f;
#pragma unroll
        for (int r = 0; r < 4; ++r) {
            if (bg[r] < 0) break;
            float v = fmaxf(fmaf(dv[r], acc[nt][r], bv), 0.f);
            if (bg[r] != g) {
                if (g >= 0) atomicAdd(&pool[g * HD + n], accf);
                accf = 0.f; g = bg[r];
            }
            accf += v;
        }
        if (g >= 0) atomicAdd(&pool[g * HD + n], accf);
    }
}

__device__ __forceinline__ int lb_dev(const int* __restrict__ b, int n, int key) {
    int lo = 0, hi = n;
    while (lo < hi) {
        int mid = (lo + hi) >> 1;
        if (b[mid] < key) lo = mid + 1; else hi = mid;
    }
    return lo;
}

__global__ void final_k(const float* __restrict__ pool, const int* __restrict__ batch,
                        const float* __restrict__ Wlin, const float* __restrict__ blin,
                        float* __restrict__ out) {
    int g = blockIdx.x;
    int lane = threadIdx.x;
    int lo = lb_dev(batch, NN, g);
    int hi = lb_dev(batch, NN, g + 1);
    float cnt = (float)(hi - lo);
    float v = pool[g * HD + lane] * Wlin[lane];
#pragma unroll
    for (int off = 32; off > 0; off >>= 1) v += __shfl_down(v, off);
    if (lane == 0) out[g] = v / fmaxf(cnt, 1.0f) + blin[0];
}

// ---------------- launch ----------------

extern "C" void kernel_launch(void* const* d_in, const int* in_sizes, int n_in,
                              void* d_out, int out_size, void* d_ws, size_t ws_size,
                              hipStream_t stream) {
    const float* x    = (const float*)d_in[0];
    const int*   ei   = (const int*)d_in[1];
    const int*   bat  = (const int*)d_in[2];
    const float* W1   = (const float*)d_in[3];
    const float* b1   = (const float*)d_in[4];
    const float* W2   = (const float*)d_in[5];
    const float* b2   = (const float*)d_in[6];
    const float* Wlin = (const float*)d_in[7];
    const float* blin = (const float*)d_in[8];
    float* out = (float*)d_out;

    const int* src = ei;
    const int* dst = ei + NE;

    char* ws = (char*)d_ws;
    size_t off = 0;
    auto alloc = [&](size_t bytes) {
        char* p = ws + off;
        off += (bytes + 255) & ~(size_t)255;
        return p;
    };
    int*   bcur    = (int*)  alloc((NBUK + 1) * sizeof(int));
    int*   row_beg = (int*)  alloc(NN * sizeof(int));
    int*   row_deg = (int*)  alloc(NN * sizeof(int));
    float* dinv    = (float*)alloc(NN * sizeof(float));
    unsigned int* edges2 = (unsigned int*)alloc((size_t)NBUK * CAP * sizeof(unsigned int)); // 14.4 MB
    float4* xs     = (float4*)alloc((size_t)NN * sizeof(float4));
    __half* h1     = (__half*)alloc((size_t)NN * HD * sizeof(__half));
    __half* a2h    = (__half*)alloc((size_t)NN * HD * sizeof(__half));
    _Float16* W2t  = (_Float16*)alloc(HD * HD * sizeof(_Float16));
    float* pool    = (float*)alloc((size_t)NG * HD * sizeof(float));
    (void)ws_size; (void)n_in; (void)in_sizes; (void)out_size;

    const int BLK = 256;
    const int gW = (NN * 64 + BLK - 1) / BLK;   // one wave per node

    // build: bucket runs -> in-place fine sort (+ W2 transpose/convert)
    init_k<<<(NBUK + 1 + 255) / 256, 256, 0, stream>>>(bcur);
    w2t_k<<<16, 256, 0, stream>>>(W2, W2t);
    stageA_k<<<NB, 512, 0, stream>>>(src, dst, bcur, edges2);
    build1_k<<<NBUK, 512, 0, stream>>>(bcur, (const float4*)x, edges2,
                                       row_beg, row_deg, dinv, xs);

    // layer 1 fused: gather + W1 GEMM -> fp16 h1
    g1f_k<<<gW, BLK, 0, stream>>>(xs, edges2, row_beg, row_deg, dinv, W1, b1, h1);

    // layer 2: wide-load gather, fp16 packed accumulation -> fp16 a2
    gather2_k<<<gW, BLK, 0, stream>>>(h1, edges2, row_beg, row_deg, a2h);

    // combine + pool + readout (MFMA GEMM, 64 nodes per block)
    hipMemsetAsync(pool, 0, (size_t)NG * HD * sizeof(float), stream);
    c2mfma_k<<<(NN + 63) / 64, 256, 0, stream>>>(a2h, W2t, b2, dinv, bat, pool);
    final_k<<<NG, 64, 0, stream>>>(pool, bat, Wlin, blin, out);
}